// Round 6
// baseline (1073.867 us; speedup 1.0000x reference)
//
#include <hip/hip_runtime.h>
#include <hip/hip_bf16.h>

#define NN 100000
#define EE 1600000
#define ET (EE + NN)
#define NBK 1563  // ceil(NN/64) coarse buckets (64 nodes each)

typedef unsigned short ushort_t;
typedef short short8 __attribute__((ext_vector_type(8)));
typedef float f32x4 __attribute__((ext_vector_type(4)));

static __device__ __forceinline__ float b2f(unsigned short u) {
    return __uint_as_float(((unsigned int)u) << 16);
}
static __device__ __forceinline__ unsigned short f2b(float f) {
    unsigned int x = __float_as_uint(f);
    return (unsigned short)((x + 0x7fffu + ((x >> 16) & 1u)) >> 16);
}

// ---------------- fp32->bf16 transpose: W1 [512,64] -> W1T [64,512]; W2 [64,128] -> W2T [128,64]
__global__ __launch_bounds__(256) void ktrans(const float* __restrict__ W1,
                                              const float* __restrict__ W2,
                                              ushort_t* __restrict__ W1T,
                                              ushort_t* __restrict__ W2T) {
    int tid = blockIdx.x * 256 + threadIdx.x;
    if (tid < 32768) {
        int k = tid >> 6, c = tid & 63;
        W1T[c * 512 + k] = f2b(W1[tid]);
    } else if (tid < 40960) {
        int t = tid - 32768;
        int k = t >> 7, c = t & 127;
        W2T[c * 64 + k] = f2b(W2[t]);
    }
}

// ---------------- GEMM1: h1[N,64] = x[N,512] @ W1  (fp32 x -> bf16 MFMA, fp32 acc)
__global__ __launch_bounds__(256) void kgemm1(const float* __restrict__ x,
                                              const ushort_t* __restrict__ w1t,
                                              ushort_t* __restrict__ h1) {
    __shared__ __align__(16) ushort_t xs[64][136];
    const int tid = threadIdx.x;
    const int wid = tid >> 6, lane = tid & 63;
    const int l15 = lane & 15, qq = lane >> 4;
    const int row0 = blockIdx.x * 64;
    f32x4 acc[4];
#pragma unroll
    for (int i = 0; i < 4; ++i) acc[i] = (f32x4)0.f;
    for (int kc = 0; kc < 4; ++kc) {
        float4 f[8];
#pragma unroll
        for (int i = 0; i < 8; ++i) {
            int f4i = tid + 256 * i;
            int rr = f4i >> 5;
            int cc = f4i & 31;
            long gr = (long)min(row0 + rr, NN - 1);
            f[i] = *(const float4*)(x + gr * 512 + kc * 128 + cc * 4);
        }
        __syncthreads();
#pragma unroll
        for (int i = 0; i < 8; ++i) {
            int f4i = tid + 256 * i;
            int rr = f4i >> 5, cc = f4i & 31;
            uint2 uu;
            uu.x = ((unsigned)f2b(f[i].y) << 16) | f2b(f[i].x);
            uu.y = ((unsigned)f2b(f[i].w) << 16) | f2b(f[i].z);
            *(uint2*)&xs[rr][cc * 4] = uu;
        }
        __syncthreads();
#pragma unroll
        for (int ks = 0; ks < 4; ++ks) {
            short8 b = *(const short8*)(w1t + (size_t)(wid * 16 + l15) * 512 + kc * 128 + ks * 32 + qq * 8);
#pragma unroll
            for (int mt = 0; mt < 4; ++mt) {
                short8 a = *(const short8*)&xs[mt * 16 + l15][ks * 32 + qq * 8];
                acc[mt] = __builtin_amdgcn_mfma_f32_16x16x32_bf16(a, b, acc[mt], 0, 0, 0);
            }
        }
    }
#pragma unroll
    for (int mt = 0; mt < 4; ++mt) {
        int node = row0 + mt * 16 + qq * 4;
#pragma unroll
        for (int rr = 0; rr < 4; ++rr) {
            if (node + rr < NN)
                h1[(size_t)(node + rr) * 64 + wid * 16 + l15] = f2b(acc[mt][rr]);
        }
    }
}

// ---------------- GEMM2: h2[N,128] = hin[N,64] @ W2  (bf16 in/out)
__global__ __launch_bounds__(256) void kgemm2(const ushort_t* __restrict__ hin,
                                              const ushort_t* __restrict__ w2t,
                                              ushort_t* __restrict__ h2) {
    __shared__ __align__(16) ushort_t xs[64][72];
    const int tid = threadIdx.x;
    const int wid = tid >> 6, lane = tid & 63;
    const int l15 = lane & 15, qq = lane >> 4;
    const int row0 = blockIdx.x * 64;
    const int r = tid >> 2, seg = tid & 3;
    const long grow = (long)min(row0 + r, NN - 1);
    const uint4* gp = (const uint4*)(hin + grow * 64 + seg * 16);
    uint4 v0 = gp[0], v1 = gp[1];
    uint4* lp = (uint4*)&xs[r][seg * 16];
    lp[0] = v0; lp[1] = v1;
    __syncthreads();
    f32x4 acc[4][2];
#pragma unroll
    for (int i = 0; i < 4; ++i)
#pragma unroll
        for (int j = 0; j < 2; ++j) acc[i][j] = (f32x4)0.f;
#pragma unroll
    for (int ks = 0; ks < 2; ++ks) {
        short8 a[4];
#pragma unroll
        for (int mt = 0; mt < 4; ++mt)
            a[mt] = *(const short8*)&xs[mt * 16 + l15][ks * 32 + qq * 8];
#pragma unroll
        for (int nt = 0; nt < 2; ++nt) {
            short8 b = *(const short8*)(w2t + (size_t)(wid * 32 + nt * 16 + l15) * 64 + ks * 32 + qq * 8);
#pragma unroll
            for (int mt = 0; mt < 4; ++mt)
                acc[mt][nt] = __builtin_amdgcn_mfma_f32_16x16x32_bf16(a[mt], b, acc[mt][nt], 0, 0, 0);
        }
    }
#pragma unroll
    for (int mt = 0; mt < 4; ++mt) {
        int node = row0 + mt * 16 + qq * 4;
#pragma unroll
        for (int nt = 0; nt < 2; ++nt) {
            int col = wid * 32 + nt * 16 + l15;
#pragma unroll
            for (int rr = 0; rr < 4; ++rr) {
                if (node + rr < NN)
                    h2[(size_t)(node + rr) * 128 + col] = f2b(acc[mt][nt][rr]);
            }
        }
    }
}

// ================= CSR build (two-level bucket, low write-amplification) =================
// coarse histogram over NBK buckets (dst>>6)
__global__ __launch_bounds__(256) void kcoarse(const int* __restrict__ ei, int* __restrict__ chist) {
    int e = blockIdx.x * 256 + threadIdx.x;
    if (e >= ET) return;
    int dst = (e < EE) ? ei[EE + e] : (e - EE);
    atomicAdd(&chist[dst >> 6], 1);
}

// single-block scan of NBK bucket counts -> cbase (exclusive), ccur (cursor copy)
__global__ __launch_bounds__(256) void kscan(const int* __restrict__ chist,
                                             int* __restrict__ cbase, int* __restrict__ ccur) {
    __shared__ int lds[NBK];
    __shared__ int part[256];
    int t = threadIdx.x;
    for (int i = t; i < NBK; i += 256) lds[i] = chist[i];
    __syncthreads();
    int c0 = t * 7, c1 = min(c0 + 7, NBK);
    int s = 0;
    for (int i = c0; i < c1; ++i) s += lds[i];
    part[t] = s;
    __syncthreads();
    if (t == 0) { int run = 0; for (int i = 0; i < 256; ++i) { int v = part[i]; part[i] = run; run += v; } }
    __syncthreads();
    int off = part[t];
    for (int i = c0; i < c1; ++i) { int v = lds[i]; cbase[i] = off; ccur[i] = off; off += v; }
    if (t == 0) cbase[NBK] = ET;
}

// coarse scatter: (src,dst) records into bucket regions (cursor-sequential -> L2-coalesced writes)
__global__ __launch_bounds__(256) void kcscatter(const int* __restrict__ ei, int* __restrict__ ccur,
                                                 uint2* __restrict__ recs) {
    int e = blockIdx.x * 256 + threadIdx.x;
    if (e >= ET) return;
    int src, dst;
    if (e < EE) { src = ei[e]; dst = ei[EE + e]; } else { src = dst = e - EE; }
    int pos = atomicAdd(&ccur[dst >> 6], 1);
    recs[pos] = make_uint2((unsigned)src, (unsigned)dst);
}

// per-bucket fine pass: LDS histogram+scan over 64 nodes, emit rowp + final srt
__global__ __launch_bounds__(256) void klocal(const uint2* __restrict__ recs,
                                              const int* __restrict__ cbase,
                                              int* __restrict__ rowp, int* __restrict__ srt) {
    __shared__ int cnt[64];
    __shared__ int cur[64];
    int t = threadIdx.x, b = blockIdx.x;
    int base = cbase[b], end = cbase[b + 1];
    if (t < 64) cnt[t] = 0;
    __syncthreads();
    for (int i = base + t; i < end; i += 256)
        atomicAdd(&cnt[recs[i].y & 63], 1);
    __syncthreads();
    if (t == 0) { int run = base; for (int l = 0; l < 64; ++l) { cur[l] = run; run += cnt[l]; } }
    __syncthreads();
    if (t < 64) {
        int node = b * 64 + t;
        if (node <= NN) rowp[node] = cur[t];  // node==NN lands in last bucket with cur==ET
    }
    __syncthreads();
    for (int i = base + t; i < end; i += 256) {
        uint2 r = recs[i];
        int pos = atomicAdd(&cur[r.y & 63], 1);
        srt[pos] = (int)r.x;
    }
}

// ================= layer-1 fused agg: softmax-weighted sum + bias + PReLU -> hin (bf16)
__global__ __launch_bounds__(256) void kagg1(const int* __restrict__ rowp,
                                             const int* __restrict__ srt,
                                             const ushort_t* __restrict__ h1,
                                             const float* __restrict__ aws,
                                             const float* __restrict__ awd,
                                             const float* __restrict__ b1,
                                             const float* __restrict__ pw,
                                             ushort_t* __restrict__ hin) {
    int tid = blockIdx.x * 256 + threadIdx.x;  // exactly N*8
    int n = tid >> 3, h = tid & 7;
    float as_w[8], ad_w[8];
#pragma unroll
    for (int c = 0; c < 8; ++c) { as_w[c] = aws[h * 8 + c]; ad_w[c] = awd[h * 8 + c]; }
    uint4 hd = *(const uint4*)(h1 + (size_t)n * 64 + h * 8);
    const ushort_t* hdp = (const ushort_t*)&hd;
    float ad = 0.f;
#pragma unroll
    for (int c = 0; c < 8; ++c) ad += b2f(hdp[c]) * ad_w[c];
    int j0 = rowp[n], j1 = rowp[n + 1];
    float num[8]; float den = 0.f;
#pragma unroll
    for (int c = 0; c < 8; ++c) num[c] = 0.f;
    for (int j = j0; j < j1; ++j) {
        int s = srt[j];
        uint4 hv = *(const uint4*)(h1 + (size_t)s * 64 + h * 8);
        const ushort_t* hp = (const ushort_t*)&hv;
        float va[8];
#pragma unroll
        for (int c = 0; c < 8; ++c) va[c] = b2f(hp[c]);
        float sc = ad;
#pragma unroll
        for (int c = 0; c < 8; ++c) sc += va[c] * as_w[c];
        sc = (sc >= 0.f) ? sc : 0.2f * sc;
        float w = __expf(sc);
        den += w;
#pragma unroll
        for (int c = 0; c < 8; ++c) num[c] += w * va[c];
    }
    float inv = 1.f / den;
    float pwf = pw[0];
    ushort_t o[8];
#pragma unroll
    for (int c = 0; c < 8; ++c) {
        float v = num[c] * inv + b1[h * 8 + c];
        v = (v >= 0.f) ? v : pwf * v;
        o[c] = f2b(v);
    }
    *(uint4*)(hin + (size_t)n * 64 + h * 8) = *(uint4*)o;
}

// ================= layer-2 fused agg: softmax sum + head-mean + bias + log_softmax -> out (fp32)
__global__ __launch_bounds__(256) void kagg2(const int* __restrict__ rowp,
                                             const int* __restrict__ srt,
                                             const ushort_t* __restrict__ h2,
                                             const float* __restrict__ aws,
                                             const float* __restrict__ awd,
                                             const float* __restrict__ b2,
                                             float* __restrict__ out) {
    __shared__ float red[32][17];
    int t = threadIdx.x;
    int nl = t >> 3, h = t & 7;
    int n = blockIdx.x * 32 + nl;  // grid 3125*32 == NN exactly
    for (int i = t; i < 32 * 17; i += 256) ((float*)red)[i] = 0.f;
    __syncthreads();
    float as_w[16], ad_w[16];
#pragma unroll
    for (int c = 0; c < 16; ++c) { as_w[c] = aws[h * 16 + c]; ad_w[c] = awd[h * 16 + c]; }
    uint4 d0 = *(const uint4*)(h2 + (size_t)n * 128 + h * 16);
    uint4 d1 = *(const uint4*)(h2 + (size_t)n * 128 + h * 16 + 8);
    const ushort_t* dp0 = (const ushort_t*)&d0;
    const ushort_t* dp1 = (const ushort_t*)&d1;
    float ad = 0.f;
#pragma unroll
    for (int c = 0; c < 8; ++c) { ad += b2f(dp0[c]) * ad_w[c]; ad += b2f(dp1[c]) * ad_w[8 + c]; }
    int j0 = rowp[n], j1 = rowp[n + 1];
    float num[16]; float den = 0.f;
#pragma unroll
    for (int c = 0; c < 16; ++c) num[c] = 0.f;
    for (int j = j0; j < j1; ++j) {
        int s = srt[j];
        uint4 v0 = *(const uint4*)(h2 + (size_t)s * 128 + h * 16);
        uint4 v1 = *(const uint4*)(h2 + (size_t)s * 128 + h * 16 + 8);
        const ushort_t* p0 = (const ushort_t*)&v0;
        const ushort_t* p1 = (const ushort_t*)&v1;
        float va[16];
#pragma unroll
        for (int c = 0; c < 8; ++c) { va[c] = b2f(p0[c]); va[8 + c] = b2f(p1[c]); }
        float sc = ad;
#pragma unroll
        for (int c = 0; c < 16; ++c) sc += va[c] * as_w[c];
        sc = (sc >= 0.f) ? sc : 0.2f * sc;
        float w = __expf(sc);
        den += w;
#pragma unroll
        for (int c = 0; c < 16; ++c) num[c] += w * va[c];
    }
    float sden = 0.125f / den;
#pragma unroll
    for (int k = 0; k < 16; ++k) {
        int c = (h * 2 + k) & 15;
        atomicAdd(&red[nl][c], num[c] * sden);
    }
    __syncthreads();
    if (t < 32) {
        float v[16];
#pragma unroll
        for (int d = 0; d < 16; ++d) v[d] = red[t][d] + b2[d];
        float m = v[0];
#pragma unroll
        for (int d = 1; d < 16; ++d) m = fmaxf(m, v[d]);
        float sum = 0.f;
#pragma unroll
        for (int d = 0; d < 16; ++d) sum += __expf(v[d] - m);
        float ls = __logf(sum) + m;
        float* op = out + (size_t)(blockIdx.x * 32 + t) * 16;
#pragma unroll
        for (int d = 0; d < 16; ++d) op[d] = v[d] - ls;
    }
}

extern "C" void kernel_launch(void* const* d_in, const int* in_sizes, int n_in,
                              void* d_out, int out_size, void* d_ws, size_t ws_size,
                              hipStream_t stream) {
    const float* x    = (const float*)d_in[0];
    const int*   ei   = (const int*)d_in[1];
    const float* W1   = (const float*)d_in[2];
    const float* aws1 = (const float*)d_in[3];
    const float* awd1 = (const float*)d_in[4];
    const float* b1   = (const float*)d_in[5];
    const float* pw   = (const float*)d_in[6];
    const float* W2   = (const float*)d_in[7];
    const float* aws2 = (const float*)d_in[8];
    const float* awd2 = (const float*)d_in[9];
    const float* b2   = (const float*)d_in[10];
    float* out = (float*)d_out;

    // Arena (47.3 MB peak):
    //   [ 0.0 -  6.8M) srt (ET int)
    //   [ 6.8 -  7.2M) rowp (N+1 int)
    //   [ 7.20M+) chist / cbase / ccur (NBK(+1) ints each)
    //   [ 8.0 - 20.8M) hin (bf16)
    //   [20.8 - 33.6M) h1 (bf16)        [dead after kagg1]
    //   [20.8 - 46.4M) h2 (bf16)        [written by kgemm2, after recs dead]
    //   [33.6 - 47.2M) recs (uint2×ET)  [dead after klocal]
    //   [47.2M+) W1T (64KB), W2T (16KB)
    char* ws = (char*)d_ws;
    int*      srt   = (int*)(ws + 0);
    int*      rowp  = (int*)(ws + 6800000);
    int*      chist = (int*)(ws + 7200256);
    int*      cbase = (int*)(ws + 7208192);
    int*      ccur  = (int*)(ws + 7216128);
    ushort_t* hin   = (ushort_t*)(ws + 8000000);
    ushort_t* h1    = (ushort_t*)(ws + 20800000);
    ushort_t* h2    = (ushort_t*)(ws + 20800000);
    uint2*    recs  = (uint2*)(ws + 33600000);
    ushort_t* W1T   = (ushort_t*)(ws + 47200000);
    ushort_t* W2T   = (ushort_t*)(ws + 47265536);

    hipMemsetAsync(chist, 0, NBK * 4, stream);
    ktrans<<<160, 256, 0, stream>>>(W1, W2, W1T, W2T);
    kgemm1<<<1563, 256, 0, stream>>>(x, W1T, h1);
    kcoarse<<<6641, 256, 0, stream>>>(ei, chist);
    kscan<<<1, 256, 0, stream>>>(chist, cbase, ccur);
    kcscatter<<<6641, 256, 0, stream>>>(ei, ccur, recs);
    klocal<<<NBK, 256, 0, stream>>>(recs, cbase, rowp, srt);
    kagg1<<<3125, 256, 0, stream>>>(rowp, srt, h1, aws1, awd1, b1, pw, hin);
    kgemm2<<<1563, 256, 0, stream>>>(hin, W2T, h2);
    kagg2<<<3125, 256, 0, stream>>>(rowp, srt, h2, aws2, awd2, b2, out);
}